// Round 4
// baseline (238.436 us; speedup 1.0000x reference)
//
#include <hip/hip_runtime.h>
#include <hip/hip_bf16.h>

#define B_ 4
#define S_ 2048
#define D_ 1024
#define MTOT (B_ * S_)

typedef __attribute__((ext_vector_type(8))) short bf16x8;
typedef __attribute__((ext_vector_type(4))) float f32x4;

__device__ __forceinline__ unsigned short f2bf(float f) {
  union { float f; unsigned int u; } v; v.f = f;
  unsigned int r = v.u + 0x7FFFu + ((v.u >> 16) & 1u);
  return (unsigned short)(r >> 16);
}
__device__ __forceinline__ float bf2f(unsigned short u) {
  union { unsigned int u; float f; } v; v.u = ((unsigned int)u) << 16;
  return v.f;
}

// ------------- fused fp32->bf16 convert: X -> Xb, {Wq,Wk,Wv} -> Wqkv -------------
__global__ __launch_bounds__(256) void cvt_all(const float* __restrict__ X,
                                               const float* __restrict__ Wq,
                                               const float* __restrict__ Wk,
                                               const float* __restrict__ Wv,
                                               unsigned short* __restrict__ Xb,
                                               unsigned short* __restrict__ Wqkv) {
  long i = (long)blockIdx.x * 256 + threadIdx.x;  // float4 index
  const float* src;
  unsigned short* dst;
  long off;
  if (i < 2097152L) {  // X: 8M elems
    src = X; dst = Xb; off = i;
  } else {
    long j = i - 2097152L;
    int w = (int)(j >> 18);          // 262144 float4 per W
    off = j & 262143L;
    src = (w == 0) ? Wq : (w == 1) ? Wk : Wv;
    dst = Wqkv + (long)w * 1048576L;
  }
  float4 v = ((const float4*)src)[off];
  ushort4 o;
  o.x = f2bf(v.x); o.y = f2bf(v.y); o.z = f2bf(v.z); o.w = f2bf(v.w);
  ((ushort4*)dst)[off] = o;
}

// -------- row L2-normalize bf16 [8192][1024]; blockIdx.y: 0=Q->Qn, 1=K->Kn --------
__global__ __launch_bounds__(256) void rownorm_bf16(const unsigned short* __restrict__ QKraw,
                                                    unsigned short* __restrict__ Qn,
                                                    unsigned short* __restrict__ Kn) {
  int row = blockIdx.x;
  int half = blockIdx.y;
  int tid = threadIdx.x;
  const unsigned short* src = QKraw + (long)half * MTOT * D_;
  ushort4 u = *(const ushort4*)(src + (long)row * D_ + tid * 4);
  float x0 = bf2f(u.x), x1 = bf2f(u.y), x2 = bf2f(u.z), x3 = bf2f(u.w);
  float ss = x0 * x0 + x1 * x1 + x2 * x2 + x3 * x3;
#pragma unroll
  for (int o = 1; o < 64; o <<= 1) ss += __shfl_xor(ss, o);
  __shared__ float wsum[4];
  if ((tid & 63) == 0) wsum[tid >> 6] = ss;
  __syncthreads();
  float rn = rsqrtf(wsum[0] + wsum[1] + wsum[2] + wsum[3]);
  ushort4 o;
  o.x = f2bf(x0 * rn); o.y = f2bf(x1 * rn); o.z = f2bf(x2 * rn); o.w = f2bf(x3 * rn);
  unsigned short* op = half ? Kn : Qn;
  *(ushort4*)(op + (long)row * D_ + tid * 4) = o;
}

// ================= 256x256 8-phase MFMA GEMM: C = A[M,K] @ B[N,K]^T =================
// 512 threads (8 waves, 2M x 4N), BK=64, 128KiB dynamic LDS, double-buffered.
// T2: XOR swizzle (16B-slot ^ (row&7)<<4), pre-swizzled global source + swizzled read.
// T3/T4: 4 phases/K-tile; staging SPREAD 2 loads/phase (m196 fine-interleave);
//        tile T staged at {(T-2).ph3, (T-1).ph0, (T-1).ph1, (T-1).ph2};
//        boundary wait = counted vmcnt(2) (never 0 mid-loop).
// T5: setprio(1) around each 16-MFMA cluster.
// T1: bijective XCD-chunked swizzle on flattened 1D grid.
// EPI: 0 fp32 out; 1 fused-QKV out (Q,K raw bf16 + V scattered to [b][d][s]);
//      2 bf16 * attention-mask out.

#define GLDS16(g, l)                                                                   \
  __builtin_amdgcn_global_load_lds((const __attribute__((address_space(1))) void*)(g), \
                                   (__attribute__((address_space(3))) void*)(l), 16, 0, 0)

template <int EPI, int KK>
__global__ __launch_bounds__(512, 2) void gemm8(const unsigned short* __restrict__ A,
                                                const unsigned short* __restrict__ B,
                                                void* __restrict__ Cv, int N,
                                                long strideA, long strideB, long strideC,
                                                const int* __restrict__ masks,
                                                int GXm1, int LGX, int GYm1, int LGY) {
  constexpr int NT = KK / 64;
  extern __shared__ __align__(16) char smem[];
  char* smA = smem;           // [2][32768] : 256 rows x 128B, swizzled
  char* smB = smem + 65536;   // [2][32768]

  // ---- T1: bijective XCD-chunked block swizzle (gridDim.x % 8 == 0) ----
  const int nb8 = gridDim.x >> 3;
  const int bid = blockIdx.x;
  const int swz = (bid & 7) * nb8 + (bid >> 3);
  const int bx = swz & GXm1;
  const int rem = swz >> LGX;
  const int by = rem & GYm1;
  const int z = rem >> LGY;

  const unsigned short* Ab = A + (long)z * strideA;
  const unsigned short* Bb = B + (long)z * strideB;
  const int t = threadIdx.x;
  const int lane = t & 63, w = t >> 6;
  const int wm = w >> 2, wn = w & 3;
  const int fr = lane & 15, fq = lane >> 4;
  const int brow = bx * 256, bcol = by * 256;

  // staging: thread t covers LDS row srow(+64j), 16B slot (t&7), source pre-XOR'd
  const int srow = t >> 3;
  const int sswz = ((t & 7) * 16) ^ ((srow & 7) << 4);
  const char* gA = (const char*)(Ab + (long)(brow + srow) * KK) + sswz;
  const char* gB = (const char*)(Bb + (long)(bcol + srow) * KK) + sswz;
  const long jstr = (long)64 * KK * 2;

  // pair p of tile T: p0=A stripes{0,1}, p1=A{2,3}, p2=B{0,1}, p3=B{2,3}
#define STAGE_PAIR(T, p)                                        \
  do {                                                          \
    const int bf_ = (T) & 1;                                    \
    if ((p) == 0) {                                             \
      const char* g_ = gA + (long)(T) * 128;                    \
      char* l_ = smA + bf_ * 32768 + t * 16;                    \
      GLDS16(g_, l_); GLDS16(g_ + jstr, l_ + 8192);             \
    } else if ((p) == 1) {                                      \
      const char* g_ = gA + (long)(T) * 128 + 2 * jstr;         \
      char* l_ = smA + bf_ * 32768 + t * 16 + 16384;            \
      GLDS16(g_, l_); GLDS16(g_ + jstr, l_ + 8192);             \
    } else if ((p) == 2) {                                      \
      const char* g_ = gB + (long)(T) * 128;                    \
      char* l_ = smB + bf_ * 32768 + t * 16;                    \
      GLDS16(g_, l_); GLDS16(g_ + jstr, l_ + 8192);             \
    } else {                                                    \
      const char* g_ = gB + (long)(T) * 128 + 2 * jstr;         \
      char* l_ = smB + bf_ * 32768 + t * 16 + 16384;            \
      GLDS16(g_, l_); GLDS16(g_ + jstr, l_ + 8192);             \
    }                                                           \
  } while (0)

  const int c0 = (fq * 16) ^ ((fr & 7) << 4);
  const int c1 = c0 ^ 64;
  const int arow = (wm * 128 + fr) * 128;
  const int brw = (wn * 64 + fr) * 128;

  f32x4 acc[8][4];
#pragma unroll
  for (int m = 0; m < 8; m++)
#pragma unroll
    for (int n = 0; n < 4; n++) acc[m][n] = (f32x4){0.f, 0.f, 0.f, 0.f};
  bf16x8 af[4][2], bv[2][2][2];

#define LDA(qm)                                                               \
  do {                                                                        \
    _Pragma("unroll") for (int mf = 0; mf < 4; ++mf) {                        \
      af[mf][0] = *(const bf16x8*)(pa + c0 + (((qm)*64 + mf * 16) << 7));     \
      af[mf][1] = *(const bf16x8*)(pa + c1 + (((qm)*64 + mf * 16) << 7));     \
    }                                                                         \
  } while (0)

#define LDB(qn)                                                               \
  do {                                                                        \
    _Pragma("unroll") for (int nf = 0; nf < 2; ++nf) {                        \
      bv[(qn)][nf][0] = *(const bf16x8*)(pb + c0 + (((qn)*32 + nf * 16) << 7)); \
      bv[(qn)][nf][1] = *(const bf16x8*)(pb + c1 + (((qn)*32 + nf * 16) << 7)); \
    }                                                                         \
  } while (0)

#define MFMAQ(qm, qn)                                                         \
  do {                                                                        \
    _Pragma("unroll") for (int ks = 0; ks < 2; ++ks)                          \
    _Pragma("unroll") for (int nf = 0; nf < 2; ++nf)                          \
    _Pragma("unroll") for (int mf = 0; mf < 4; ++mf)                          \
      acc[(qm)*4 + mf][(qn)*2 + nf] = __builtin_amdgcn_mfma_f32_16x16x32_bf16(\
          af[mf][ks], bv[(qn)][nf][ks], acc[(qm)*4 + mf][(qn)*2 + nf], 0, 0, 0); \
  } while (0)

#define BARW()                                                \
  do {                                                        \
    __builtin_amdgcn_s_barrier();                             \
    asm volatile("s_waitcnt lgkmcnt(0)" ::: "memory");        \
    __builtin_amdgcn_sched_barrier(0);                        \
  } while (0)

  // prologue: tile0 fully + tile1 pair0 (the "(T-2).ph3" slot for T=1)
  STAGE_PAIR(0, 0); STAGE_PAIR(0, 1); STAGE_PAIR(0, 2); STAGE_PAIR(0, 3);
  STAGE_PAIR(1, 0);
  asm volatile("s_waitcnt vmcnt(2)" ::: "memory");
  __builtin_amdgcn_s_barrier();

#pragma unroll 2
  for (int kt = 0; kt < NT; ++kt) {
    const int cur = kt & 1;
    const char* pa = smA + cur * 32768 + arow;
    const char* pb = smB + cur * 32768 + brw;
    // ph0: quad (0,0)
    LDA(0);
    LDB(0);
    if (kt + 1 < NT) STAGE_PAIR(kt + 1, 1);
    BARW();
    __builtin_amdgcn_s_setprio(1);
    MFMAQ(0, 0);
    __builtin_amdgcn_s_setprio(0);
    __builtin_amdgcn_s_barrier();
    // ph1: quad (0,1)
    LDB(1);
    if (kt + 1 < NT) STAGE_PAIR(kt + 1, 2);
    BARW();
    __builtin_amdgcn_s_setprio(1);
    MFMAQ(0, 1);
    __builtin_amdgcn_s_setprio(0);
    __builtin_amdgcn_s_barrier();
    // ph2: quad (1,1)
    LDA(1);
    if (kt + 1 < NT) STAGE_PAIR(kt + 1, 3);
    BARW();
    __builtin_amdgcn_s_setprio(1);
    MFMAQ(1, 1);
    __builtin_amdgcn_s_setprio(0);
    __builtin_amdgcn_s_barrier();
    // ph3: quad (1,0); buf cur is read-dead -> stage next-next tile's first pair
    if (kt + 2 < NT) STAGE_PAIR(kt + 2, 0);
    BARW();
    __builtin_amdgcn_s_setprio(1);
    MFMAQ(1, 0);
    __builtin_amdgcn_s_setprio(0);
    // boundary: counted wait -> tile kt+1 fully landed
    if (kt + 1 < NT) {
      if (kt + 2 < NT)
        asm volatile("s_waitcnt vmcnt(2)" ::: "memory");
      else
        asm volatile("s_waitcnt vmcnt(0)" ::: "memory");
      __builtin_amdgcn_s_barrier();
    }
  }
#undef STAGE_PAIR
#undef LDA
#undef LDB
#undef MFMAQ
#undef BARW

  long cbase = (long)z * strideC;
#pragma unroll
  for (int Mi = 0; Mi < 8; ++Mi) {
#pragma unroll
    for (int Ni = 0; Ni < 4; ++Ni) {
#pragma unroll
      for (int r = 0; r < 4; ++r) {
        int grow = brow + wm * 128 + Mi * 16 + fq * 4 + r;
        int gcol = bcol + wn * 64 + Ni * 16 + fr;
        float v = acc[Mi][Ni][r];
        if constexpr (EPI == 0) {
          ((float*)Cv)[cbase + (long)grow * N + gcol] = v;
        } else if constexpr (EPI == 1) {
          // fused QKV: seg 0 -> Qraw, 1 -> Kraw, 2 -> Vt[b][d][s]
          unsigned short* base = (unsigned short*)Cv;
          int seg = gcol >> 10, c = gcol & 1023;
          if (seg == 0) {
            base[(long)grow * D_ + c] = f2bf(v);
          } else if (seg == 1) {
            base[(long)MTOT * D_ + (long)grow * D_ + c] = f2bf(v);
          } else {
            int b = grow >> 11, s = grow & (S_ - 1);
            base[(long)2 * MTOT * D_ + (long)b * D_ * S_ + (long)c * S_ + s] = f2bf(v);
          }
        } else {
          // keep score where (k > q) OR key is padding (masks==0); else zero
          bool keep = (gcol > grow) || (masks[z * S_ + gcol] == 0);
          ((unsigned short*)Cv)[cbase + (long)grow * N + gcol] = keep ? f2bf(v) : (unsigned short)0;
        }
      }
    }
  }
}

extern "C" void kernel_launch(void* const* d_in, const int* in_sizes, int n_in, void* d_out,
                              int out_size, void* d_ws, size_t ws_size, hipStream_t stream) {
  (void)in_sizes; (void)n_in; (void)out_size; (void)ws_size;
  const float* X = (const float*)d_in[0];
  const int* masks = (const int*)d_in[1];
  const float* Wq = (const float*)d_in[2];
  const float* Wk = (const float*)d_in[3];
  const float* Wv = (const float*)d_in[4];
  float* out = (float*)d_out;

  char* ws = (char*)d_ws;
  unsigned short* Xb = (unsigned short*)ws;     ws += (long)MTOT * D_ * 2;
  unsigned short* Wqkv = (unsigned short*)ws;   ws += (long)3 * D_ * D_ * 2;
  unsigned short* QKVraw = (unsigned short*)ws; ws += (long)3 * MTOT * D_ * 2;  // Qraw|Kraw|Vt
  unsigned short* Qn = (unsigned short*)ws;     ws += (long)MTOT * D_ * 2;
  unsigned short* Kn = (unsigned short*)ws;     ws += (long)MTOT * D_ * 2;
  unsigned short* Sm = (unsigned short*)ws;     ws += (long)B_ * S_ * S_ * 2;
  unsigned short* Vt = QKVraw + (long)2 * MTOT * D_;

  constexpr unsigned SMEM = 131072;
  (void)hipFuncSetAttribute((const void*)gemm8<1, 1024>, hipFuncAttributeMaxDynamicSharedMemorySize, SMEM);
  (void)hipFuncSetAttribute((const void*)gemm8<2, 1024>, hipFuncAttributeMaxDynamicSharedMemorySize, SMEM);
  (void)hipFuncSetAttribute((const void*)gemm8<0, 2048>, hipFuncAttributeMaxDynamicSharedMemorySize, SMEM);

  // fused converts: X + {Wq,Wk,Wv} -> Xb, Wqkv ([3][1024][1024])
  cvt_all<<<11264, 256, 0, stream>>>(X, Wq, Wk, Wv, Xb, Wqkv);

  // fused [Q|K|V] = X @ Wqkv^T  (M=8192, N=3072, K=1024; V pre-transposed)
  // grid 384 = 32 x 12 : GXm1=31, LGX=5, GYm1=15, LGY=4 (z always 0)
  gemm8<1, 1024><<<384, 512, SMEM, stream>>>(Xb, Wqkv, QKVraw, 3 * D_,
                                             0, 0, 0, nullptr, 31, 5, 15, 4);
  // normalize rows of Q and K
  rownorm_bf16<<<dim3(MTOT, 2), 256, 0, stream>>>(QKVraw, Qn, Kn);
  // S[b] = (Qn[b] @ Kn[b]^T) * mask  (grid 256 = 8 x 8 x 4)
  gemm8<2, 1024><<<256, 512, SMEM, stream>>>(Qn, Kn, Sm, S_,
                                             (long)S_ * D_, (long)S_ * D_, (long)S_ * S_,
                                             masks, 7, 3, 7, 3);
  // out[b] = S[b] @ V[b]  (A=Sm [S][S], B=Vt [D][S], fp32; grid 128 = 8 x 4 x 4)
  gemm8<0, 2048><<<128, 512, SMEM, stream>>>(Sm, Vt, out, D_,
                                             (long)S_ * S_, (long)D_ * S_, (long)S_ * D_,
                                             nullptr, 7, 3, 3, 2);
}

// Round 5
// 229.379 us; speedup vs baseline: 1.0395x; 1.0395x over previous
//
#include <hip/hip_runtime.h>
#include <hip/hip_bf16.h>

#define B_ 4
#define S_ 2048
#define D_ 1024
#define MTOT (B_ * S_)

typedef __attribute__((ext_vector_type(8))) short bf16x8;
typedef __attribute__((ext_vector_type(4))) float f32x4;

__device__ __forceinline__ unsigned short f2bf(float f) {
  union { float f; unsigned int u; } v; v.f = f;
  unsigned int r = v.u + 0x7FFFu + ((v.u >> 16) & 1u);
  return (unsigned short)(r >> 16);
}
__device__ __forceinline__ float bf2f(unsigned short u) {
  union { unsigned int u; float f; } v; v.u = ((unsigned int)u) << 16;
  return v.f;
}

// ------------- fused fp32->bf16 convert: X -> Xb, {Wq,Wk,Wv} -> Wqkv -------------
__global__ __launch_bounds__(256) void cvt_all(const float* __restrict__ X,
                                               const float* __restrict__ Wq,
                                               const float* __restrict__ Wk,
                                               const float* __restrict__ Wv,
                                               unsigned short* __restrict__ Xb,
                                               unsigned short* __restrict__ Wqkv) {
  long i = (long)blockIdx.x * 256 + threadIdx.x;  // float4 index
  const float* src;
  unsigned short* dst;
  long off;
  if (i < 2097152L) {  // X: 8M elems
    src = X; dst = Xb; off = i;
  } else {
    long j = i - 2097152L;
    int w = (int)(j >> 18);          // 262144 float4 per W
    off = j & 262143L;
    src = (w == 0) ? Wq : (w == 1) ? Wk : Wv;
    dst = Wqkv + (long)w * 1048576L;
  }
  float4 v = ((const float4*)src)[off];
  ushort4 o;
  o.x = f2bf(v.x); o.y = f2bf(v.y); o.z = f2bf(v.z); o.w = f2bf(v.w);
  ((ushort4*)dst)[off] = o;
}

// -------- row L2-normalize bf16 [8192][1024]; blockIdx.y: 0=Q->Qn, 1=K->Kn --------
__global__ __launch_bounds__(256) void rownorm_bf16(const unsigned short* __restrict__ QKraw,
                                                    unsigned short* __restrict__ Qn,
                                                    unsigned short* __restrict__ Kn) {
  int row = blockIdx.x;
  int half = blockIdx.y;
  int tid = threadIdx.x;
  const unsigned short* src = QKraw + (long)half * MTOT * D_;
  ushort4 u = *(const ushort4*)(src + (long)row * D_ + tid * 4);
  float x0 = bf2f(u.x), x1 = bf2f(u.y), x2 = bf2f(u.z), x3 = bf2f(u.w);
  float ss = x0 * x0 + x1 * x1 + x2 * x2 + x3 * x3;
#pragma unroll
  for (int o = 1; o < 64; o <<= 1) ss += __shfl_xor(ss, o);
  __shared__ float wsum[4];
  if ((tid & 63) == 0) wsum[tid >> 6] = ss;
  __syncthreads();
  float rn = rsqrtf(wsum[0] + wsum[1] + wsum[2] + wsum[3]);
  ushort4 o;
  o.x = f2bf(x0 * rn); o.y = f2bf(x1 * rn); o.z = f2bf(x2 * rn); o.w = f2bf(x3 * rn);
  unsigned short* op = half ? Kn : Qn;
  *(ushort4*)(op + (long)row * D_ + tid * 4) = o;
}

// ========== 128xBN MFMA GEMM, triple-buffered LDS, counted-vmcnt pipeline ==========
// C[M,N] = A[M,K] @ B[N,K]^T.  256 threads (4 waves 2x2), BK=32.
// Tile kt+2 staged at TOP of iter kt (prefetch distance 2, ~2 iters > HBM latency);
// iter ends with counted s_waitcnt vmcnt(LD) + RAW s_barrier (no vmcnt(0) drain).
// ds_reads are ordered by the compiler's own lgkmcnt before MFMA use.
// EPI: 0 fp32 out; 1 fused-QKV (Q,K raw bf16 + V scattered to [b][d][s]); 2 bf16*mask.

#define GLDS16(g, l)                                                                   \
  __builtin_amdgcn_global_load_lds((const __attribute__((address_space(1))) void*)(g), \
                                   (__attribute__((address_space(3))) void*)(l), 16, 0, 0)

template <int EPI, int BN>
__global__ __launch_bounds__(256, 3) void gemm_tb(const unsigned short* __restrict__ A,
                                                  const unsigned short* __restrict__ B,
                                                  void* __restrict__ Cv, int N, int K,
                                                  long strideA, long strideB, long strideC,
                                                  const int* __restrict__ masks) {
  constexpr int NB = BN / 32;                 // B-frags per wave (4 or 2)
  constexpr int LD = (BN == 128) ? 4 : 3;     // global_load_lds per tile
  constexpr int ASLOT = 128 * 32 * 2;         // bytes per A slot (8KB)
  constexpr int BSLOT = BN * 32 * 2;          // bytes per B slot (8/4KB)
  __shared__ __align__(16) short lA[3][128 * 32];
  __shared__ __align__(16) short lB[3][BN * 32];

  const int z = blockIdx.z;
  const unsigned short* Ab = A + (long)z * strideA;
  const unsigned short* Bb = B + (long)z * strideB;
  const int t = threadIdx.x;
  const int lane = t & 63, w = t >> 6;
  const int wr = w >> 1, wc = w & 1;
  const int fr = lane & 15, fq = lane >> 4;
  const int brow = blockIdx.x * 128, bcol = blockIdx.y * BN;

  // staging: thread t -> row t>>2 (and +64), 16B slot t&3; LDS linear [rows][32]
  const char* gAs = (const char*)(Ab + (long)(brow + (t >> 2)) * K) + ((t & 3) << 4);
  const char* gBs = (const char*)(Bb + (long)(bcol + (t >> 2)) * K) + ((t & 3) << 4);
  const long astr = (long)64 * K * 2;  // +64 rows, bytes
  char* lAw = (char*)&lA[0][0] + (w << 10);
  char* lBw = (char*)&lB[0][0] + (w << 10);

#define STAGE(slot)                                                 \
  do {                                                              \
    GLDS16(gAs, lAw + (slot) * ASLOT);                              \
    GLDS16(gAs + astr, lAw + (slot) * ASLOT + 4096);                \
    GLDS16(gBs, lBw + (slot) * BSLOT);                              \
    if constexpr (BN == 128) GLDS16(gBs + astr, lBw + (slot) * BSLOT + 4096); \
    gAs += 64;                                                      \
    gBs += 64;                                                      \
  } while (0)

  f32x4 acc[4][NB];
#pragma unroll
  for (int m = 0; m < 4; m++)
#pragma unroll
    for (int n = 0; n < NB; n++) acc[m][n] = (f32x4){0.f, 0.f, 0.f, 0.f};

  const int NT = K / 32;
  // prologue: tiles 0,1 in flight; wait tile 0 only (counted)
  STAGE(0);
  STAGE(1);
  asm volatile("s_waitcnt vmcnt(%0)" ::"i"(LD) : "memory");
  __builtin_amdgcn_s_barrier();
  __builtin_amdgcn_sched_barrier(0);

  int cs = 0, ss = 2;
  const int arow0 = (wr * 64 + fr) * 32 + fq * 8;
  const int brow0 = (wc * (BN / 2) + fr) * 32 + fq * 8;
  for (int kt = 0; kt < NT; ++kt) {
    if (kt + 2 < NT) STAGE(ss);  // prefetch distance 2, lands ~2 iters later
    const short* pa = (const short*)((const char*)&lA[0][0] + cs * ASLOT) + arow0;
    const short* pb = (const short*)((const char*)&lB[0][0] + cs * BSLOT) + brow0;
    bf16x8 af[4], bv[NB];
#pragma unroll
    for (int m = 0; m < 4; m++) af[m] = *(const bf16x8*)(pa + m * 16 * 32);
#pragma unroll
    for (int n = 0; n < NB; n++) bv[n] = *(const bf16x8*)(pb + n * 16 * 32);
#pragma unroll
    for (int m = 0; m < 4; m++)
#pragma unroll
      for (int n = 0; n < NB; n++)
        acc[m][n] = __builtin_amdgcn_mfma_f32_16x16x32_bf16(af[m], bv[n], acc[m][n], 0, 0, 0);
    if (kt + 1 < NT) {
      if (kt + 2 < NT)
        asm volatile("s_waitcnt vmcnt(%0)" ::"i"(LD) : "memory");  // tile kt+1 landed
      else
        asm volatile("s_waitcnt vmcnt(0)" ::: "memory");           // last tile
      __builtin_amdgcn_s_barrier();
      __builtin_amdgcn_sched_barrier(0);
    }
    cs = (cs == 2) ? 0 : cs + 1;
    ss = (ss == 2) ? 0 : ss + 1;
  }
#undef STAGE

  long cbase = (long)z * strideC;
#pragma unroll
  for (int m = 0; m < 4; m++) {
#pragma unroll
    for (int n = 0; n < NB; n++) {
#pragma unroll
      for (int r = 0; r < 4; r++) {
        int grow = brow + wr * 64 + m * 16 + fq * 4 + r;
        int gcol = bcol + wc * (BN / 2) + n * 16 + fr;
        float v = acc[m][n][r];
        if constexpr (EPI == 0) {
          ((float*)Cv)[cbase + (long)grow * N + gcol] = v;
        } else if constexpr (EPI == 1) {
          // fused QKV: seg 0 -> Qraw, 1 -> Kraw, 2 -> Vt[b][d][s]
          unsigned short* base = (unsigned short*)Cv;
          int seg = gcol >> 10, c = gcol & 1023;
          if (seg == 0) {
            base[(long)grow * D_ + c] = f2bf(v);
          } else if (seg == 1) {
            base[(long)MTOT * D_ + (long)grow * D_ + c] = f2bf(v);
          } else {
            int b = grow >> 11, s = grow & (S_ - 1);
            base[(long)2 * MTOT * D_ + (long)b * D_ * S_ + (long)c * S_ + s] = f2bf(v);
          }
        } else {
          // keep score where (k > q) OR key is padding (masks==0); else zero
          bool keep = (gcol > grow) || (masks[z * S_ + gcol] == 0);
          ((unsigned short*)Cv)[cbase + (long)grow * N + gcol] = keep ? f2bf(v) : (unsigned short)0;
        }
      }
    }
  }
}

extern "C" void kernel_launch(void* const* d_in, const int* in_sizes, int n_in, void* d_out,
                              int out_size, void* d_ws, size_t ws_size, hipStream_t stream) {
  (void)in_sizes; (void)n_in; (void)out_size; (void)ws_size;
  const float* X = (const float*)d_in[0];
  const int* masks = (const int*)d_in[1];
  const float* Wq = (const float*)d_in[2];
  const float* Wk = (const float*)d_in[3];
  const float* Wv = (const float*)d_in[4];
  float* out = (float*)d_out;

  char* ws = (char*)d_ws;
  unsigned short* Xb = (unsigned short*)ws;     ws += (long)MTOT * D_ * 2;
  unsigned short* Wqkv = (unsigned short*)ws;   ws += (long)3 * D_ * D_ * 2;
  unsigned short* QKVraw = (unsigned short*)ws; ws += (long)3 * MTOT * D_ * 2;  // Qraw|Kraw|Vt
  unsigned short* Qn = (unsigned short*)ws;     ws += (long)MTOT * D_ * 2;
  unsigned short* Kn = (unsigned short*)ws;     ws += (long)MTOT * D_ * 2;
  unsigned short* Sm = (unsigned short*)ws;     ws += (long)B_ * S_ * S_ * 2;
  unsigned short* Vt = QKVraw + (long)2 * MTOT * D_;

  // fused converts: X + {Wq,Wk,Wv} -> Xb, Wqkv ([3][1024][1024])
  cvt_all<<<11264, 256, 0, stream>>>(X, Wq, Wk, Wv, Xb, Wqkv);

  // fused [Q|K|V] = X @ Wqkv^T  (M=8192, N=3072, K=1024; V pre-transposed)
  gemm_tb<1, 128><<<dim3(MTOT / 128, 3 * D_ / 128, 1), 256, 0, stream>>>(
      Xb, Wqkv, QKVraw, 3 * D_, D_, 0, 0, 0, nullptr);
  // normalize rows of Q and K
  rownorm_bf16<<<dim3(MTOT, 2), 256, 0, stream>>>(QKVraw, Qn, Kn);
  // S[b] = (Qn[b] @ Kn[b]^T) * mask  (grid 16x16x4 = 1024)
  gemm_tb<2, 128><<<dim3(S_ / 128, S_ / 128, B_), 256, 0, stream>>>(
      Qn, Kn, Sm, S_, D_, (long)S_ * D_, (long)S_ * D_, (long)S_ * S_, masks);
  // out[b] = S[b] @ V[b]  (A=Sm [S][S], B=Vt [D][S], fp32; BN=64 -> grid 16x16x4)
  gemm_tb<0, 64><<<dim3(S_ / 128, D_ / 64, B_), 256, 0, stream>>>(
      Sm, Vt, out, D_, S_, (long)S_ * S_, (long)D_ * S_, (long)S_ * D_, nullptr);
}